// Round 3
// baseline (5874.953 us; speedup 1.0000x reference)
//
#include <hip/hip_runtime.h>
#include <hip/hip_bf16.h>
#include <math.h>

#define T_LEN 1024
#define NB    128
#define L_SEQ 200
#define EMB   128
#define KSZ   128
#define VSZ   128
#define HID   512
#define G1    2048   // 4*HID
#define G2    512    // 4*KSZ
#define VOCAB 34
#define KK1   768    // EMB + VSZ + HID   (combined K for LSTM1 gates)
#define KK2   640    // HID + KSZ         (combined K for LSTM2 gates)
#define TT    64     // attention t-tile
#define NBLK  160    // persistent scan blocks (32 gates2 + 128 gates1)
#define GRP_BLKS 40  // per n-group: 8 gates2 + 32 gates1

typedef __attribute__((ext_vector_type(8))) short bf16x8;  // 8 bf16 = 4 VGPRs
typedef __attribute__((ext_vector_type(4))) float f32x4;

__device__ __forceinline__ float sig_(float x) { return 1.0f / (1.0f + __expf(-x)); }
__device__ __forceinline__ float tanh_fast(float x) {
    return 1.0f - 2.0f / (__expf(2.0f * x) + 1.0f);   // inf-safe at both ends
}

__device__ __forceinline__ f32x4 MFMA_BF16(bf16x8 a, bf16x8 b, f32x4 c) {
    return __builtin_amdgcn_mfma_f32_16x16x32_bf16(a, b, c, 0, 0, 0);
}
__device__ __forceinline__ bf16x8 LD8(const __hip_bfloat16* p) {
    return *(const bf16x8*)p;
}

// Group barrier: acq/rel atomics (compiler emits the cross-XCD L2 wb/inv),
// monotonic counter, timeout escape hatch so a residency failure can never
// hang the device (it produces a wrong-but-measurable run instead).
__device__ __forceinline__ void gbar_grp(int* bar, int tgt) {
    __syncthreads();   // everyone in the block done reading prev-phase buffers
    if (threadIdx.x == 0) {
        __hip_atomic_fetch_add(bar, 1, __ATOMIC_RELEASE, __HIP_MEMORY_SCOPE_AGENT);
        const long long t0 = __builtin_amdgcn_s_memrealtime();
        while (__hip_atomic_load(bar, __ATOMIC_ACQUIRE, __HIP_MEMORY_SCOPE_AGENT) < tgt) {
            __builtin_amdgcn_s_sleep(8);
            if (__builtin_amdgcn_s_memrealtime() - t0 > 2000000LL) break;  // ~20-70ms
        }
    }
    __syncthreads();
}

// ---------------- prep: combined bf16 weights, biases, zeroed states ----------
__global__ __launch_bounds__(256) void prep_kernel(
    const float* __restrict__ Wih1, const float* __restrict__ Whh1,
    const float* __restrict__ bih1, const float* __restrict__ bhh1,
    const float* __restrict__ Wih2, const float* __restrict__ Whh2,
    const float* __restrict__ bih2, const float* __restrict__ bhh2,
    __hip_bfloat16* __restrict__ Wc1, __hip_bfloat16* __restrict__ Wc2,
    float* __restrict__ bb1, float* __restrict__ bb2,
    __hip_bfloat16* __restrict__ h1b, __hip_bfloat16* __restrict__ h2b,
    float* __restrict__ c1, float* __restrict__ c2, int* __restrict__ bar)
{
    const int gid = blockIdx.x * 256 + threadIdx.x;
    if (gid < G1 * KK1) {
        const int o = gid / KK1, k = gid - o * KK1;
        const float v = (k < 256) ? Wih1[o * 256 + k] : Whh1[o * 512 + (k - 256)];
        Wc1[gid] = __float2bfloat16(v);
    }
    if (gid < G2 * KK2) {
        const int o = gid / KK2, k = gid - o * KK2;
        const float v = (k < 512) ? Wih2[o * 512 + k] : Whh2[o * 128 + (k - 512)];
        Wc2[gid] = __float2bfloat16(v);
    }
    if (gid < G1) bb1[gid] = bih1[gid] + bhh1[gid];
    if (gid < G2) bb2[gid] = bih2[gid] + bhh2[gid];
    if (gid < 2 * NB * HID) h1b[gid] = __float2bfloat16(0.0f);
    if (gid < 2 * NB * KSZ) h2b[gid] = __float2bfloat16(0.0f);
    if (gid < NB * HID) c1[gid] = 0.0f;
    if (gid < NB * KSZ) c2[gid] = 0.0f;
    if (gid < 256) bar[gid] = 0;            // 4 group counters, 256B apart
}

// ---------------- teacher-forced embedding gather -----------------------------
__global__ __launch_bounds__(256) void ce_gather(
    const int* __restrict__ text, const float* __restrict__ emb,
    float* __restrict__ ce_f, __hip_bfloat16* __restrict__ ce_b)
{
    const int idx = blockIdx.x * 256 + threadIdx.x;   // exact: L*N*128
    const int k = idx & 127;
    const int rn = idx >> 7;
    const int nn = rn & 127;
    const int s = rn >> 7;
    if (s >= L_SEQ) return;
    const int tok = (s == 0) ? 0 : text[nn * L_SEQ + (s - 1)];
    const float v = emb[(size_t)tok * EMB + k];
    ce_f[idx] = v;
    ce_b[idx] = __float2bfloat16(v);
}

// ---------------- q = src @ Wq.T + bq  (rows = L*N) ---------------------------
__global__ __launch_bounds__(256) void qproj_kernel(
    const float* __restrict__ src, const float* __restrict__ Wq,
    const float* __restrict__ bq, float* __restrict__ dst)
{
    __shared__ float xs[2][KSZ];
    const int tid = threadIdx.x;
    const int r0 = blockIdx.x * 2;
    xs[tid >> 7][tid & 127] = src[(size_t)(r0 + (tid >> 7)) * KSZ + (tid & 127)];
    __syncthreads();
    const int sub = tid >> 7, o = tid & 127;
    const float* wr = Wq + (size_t)o * KSZ;
    float acc = bq[o];
    #pragma unroll 8
    for (int k = 0; k < KSZ; k += 4) {
        const float4 w4 = *(const float4*)&wr[k];
        const float4 x4 = *(const float4*)&xs[sub][k];
        acc += w4.x * x4.x + w4.y * x4.y + w4.z * x4.z + w4.w * x4.w;
    }
    dst[(size_t)(r0 + sub) * KSZ + o] = acc;
}

// ---------------- flash attention: ctx = softmax(q.K^T) @ V -------------------
// grid: 512 blocks = n (128) x l-chunk (4 x 50). K/V tiled in LDS from the
// native (T,N,128) layout; online softmax; ctx accumulators in registers.
__global__ __launch_bounds__(256) void attn_kernel(
    const float* __restrict__ q,      // [L][N][KSZ]
    const float* __restrict__ key,    // [T][N][KSZ]
    const float* __restrict__ values, // [T][N][VSZ]
    const int* __restrict__ rlen,
    float* __restrict__ ctx_f,        // [L][N][VSZ]
    __hip_bfloat16* __restrict__ ctx_b)
{
    __shared__ __align__(16) float q_s[52][128];   // rows 50,51 zeroed
    __shared__ __align__(16) float Kt[TT][129];    // +1 pad: conflict-free col reads
    __shared__ __align__(16) float Vt[TT][129];
    __shared__ __align__(16) float es[52][68];     // row stride 272B (16B mult)
    __shared__ float mm[52], ss[52], al[52];
    const int tid = threadIdx.x;
    const int n = blockIdx.x >> 2;
    const int l0 = (blockIdx.x & 3) * 50;
    const int len = rlen[n];

    for (int idx = tid; idx < 52 * 128; idx += 256) {
        const int l = idx >> 7, k = idx & 127;
        q_s[l][k] = (l < 50) ? q[((size_t)(l0 + l) * NB + n) * KSZ + k] : 0.0f;
    }
    for (int l = tid; l < 52; l += 256) { mm[l] = -3.0e38f; ss[l] = 0.0f; }
    float acc[25];
    #pragma unroll
    for (int j = 0; j < 25; ++j) acc[j] = 0.0f;
    __syncthreads();

    const int lg = tid >> 6, lane = tid & 63;
    const int vv = tid & 127, hh = tid >> 7;
    const int nt = (len + TT - 1) / TT;

    for (int tt = 0; tt < nt; ++tt) {
        const int tb = tt * TT;
        const int valid = min(TT, len - tb);
        // ---- load K,V tiles (zero-fill invalid rows: LDS junk may be NaN) ----
        #pragma unroll
        for (int it = 0; it < 8; ++it) {
            const int idx4 = tid + it * 256;          // 2048 float4 slots
            const int r = idx4 >> 5, c4 = (idx4 & 31) * 4;
            float4 kq = make_float4(0.f, 0.f, 0.f, 0.f);
            float4 vq = make_float4(0.f, 0.f, 0.f, 0.f);
            if (r < valid) {
                const size_t base = ((size_t)(tb + r) * NB + n) * 128 + c4;
                kq = *(const float4*)&key[base];
                vq = *(const float4*)&values[base];
            }
            Kt[r][c4 + 0] = kq.x; Kt[r][c4 + 1] = kq.y;
            Kt[r][c4 + 2] = kq.z; Kt[r][c4 + 3] = kq.w;
            Vt[r][c4 + 0] = vq.x; Vt[r][c4 + 1] = vq.y;
            Vt[r][c4 + 2] = vq.z; Vt[r][c4 + 3] = vq.w;
        }
        __syncthreads();
        // ---- energies + online softmax: wave lg owns l = lg*13 + j ----------
        {
            float e[13];
            #pragma unroll
            for (int j = 0; j < 13; ++j) e[j] = 0.0f;
            for (int k4 = 0; k4 < 128; k4 += 4) {
                const float c0 = Kt[lane][k4 + 0], c1 = Kt[lane][k4 + 1];
                const float c2 = Kt[lane][k4 + 2], c3 = Kt[lane][k4 + 3];
                #pragma unroll
                for (int j = 0; j < 13; ++j) {
                    const float4 q4 = *(const float4*)&q_s[lg * 13 + j][k4];
                    e[j] += c0 * q4.x + c1 * q4.y + c2 * q4.z + c3 * q4.w;
                }
            }
            #pragma unroll
            for (int j = 0; j < 13; ++j) {
                const int l = lg * 13 + j;
                float ev = (lane < valid) ? e[j] : -3.0e38f;
                #pragma unroll
                for (int off = 32; off; off >>= 1) ev = fmaxf(ev, __shfl_xor(ev, off, 64));
                const float mold = mm[l];
                const float mnew = fmaxf(mold, ev);
                const float p = (lane < valid) ? __expf(e[j] - mnew) : 0.0f;
                es[l][lane] = p;
                float ps = p;
                #pragma unroll
                for (int off = 32; off; off >>= 1) ps += __shfl_xor(ps, off, 64);
                if (lane == 0) {
                    const float a = __expf(mold - mnew);   // 0 on first tile
                    al[l] = a;
                    ss[l] = ss[l] * a + ps;
                    mm[l] = mnew;
                }
            }
        }
        __syncthreads();
        // ---- PV: thread (vv, hh) owns l = hh + 2j ---------------------------
        #pragma unroll
        for (int j = 0; j < 25; ++j) {
            const int l = hh + 2 * j;
            float a = acc[j] * al[l];
            #pragma unroll 4
            for (int t4 = 0; t4 < TT; t4 += 4) {
                const float4 p4 = *(const float4*)&es[l][t4];
                a += p4.x * Vt[t4 + 0][vv] + p4.y * Vt[t4 + 1][vv]
                   + p4.z * Vt[t4 + 2][vv] + p4.w * Vt[t4 + 3][vv];
            }
            acc[j] = a;
        }
        __syncthreads();
    }
    #pragma unroll
    for (int j = 0; j < 25; ++j) {
        const int l = hh + 2 * j;
        const float r = acc[j] / ss[l];
        const size_t o = ((size_t)(l0 + l) * NB + n) * VSZ + vv;
        ctx_f[o] = r;
        ctx_b[o] = __float2bfloat16(r);
    }
}

// ---------------- persistent scan: 201 phases, weights held in VGPRs ----------
// 4 independent n-groups (32 samples each); per group 8 gates2 + 32 gates1
// blocks synced by a private group barrier (LSTM state never crosses groups).
// blocks 0..31  : gates2 (phase i computes h2(i-1), i>=1); group = bid>>3
// blocks 32..159: gates1 (phase i computes h1(i), i<200);  group = (bid-32)>>5
__global__ __launch_bounds__(256) void scan_persist(
    const __hip_bfloat16* __restrict__ Wc1, const __hip_bfloat16* __restrict__ Wc2,
    const float* __restrict__ bb1, const float* __restrict__ bb2,
    const __hip_bfloat16* __restrict__ ce_b, const __hip_bfloat16* __restrict__ ctx1_b,
    __hip_bfloat16* __restrict__ h1b, __hip_bfloat16* __restrict__ h2b,
    float* __restrict__ c1, float* __restrict__ c2,
    float* __restrict__ h2_all, int* __restrict__ bar)
{
    const int tid = threadIdx.x;
    const int w = tid >> 6;
    const int lane = tid & 63;
    const int lrow = lane & 15;
    const int krow = (lane >> 4) * 8;
    __shared__ float gl[4][32][17];

    if (blockIdx.x < 32) {
        // ================= gates2 =================
        const int grp = blockIdx.x >> 3;
        int* gb = bar + grp * 64;                 // 256B-separated counters
        const int n0 = grp * 32;
        const int og = blockIdx.x & 7;
        const int col = w * 128 + og * 16 + lrow;
        const __hip_bfloat16* brow = Wc2 + (size_t)col * KK2 + krow;
        bf16x8 wf[20];                            // 80 VGPRs, persistent
        #pragma unroll
        for (int kk = 0; kk < 20; ++kk) wf[kk] = LD8(brow + kk * 32);
        const int oc_b = og * 16 + (tid & 15);
        const float bi = bb2[oc_b],        bf_ = bb2[128 + oc_b];
        const float bg = bb2[256 + oc_b],  bo  = bb2[384 + oc_b];
        for (int i = 0; i <= L_SEQ; ++i) {
            if (i >= 1) {
                const int s2 = i - 1;
                const int rb = i & 1;
                const __hip_bfloat16* h1r = h1b + (size_t)rb * NB * HID;
                const __hip_bfloat16* h2r = h2b + (size_t)rb * NB * KSZ;
                __hip_bfloat16* h2w = h2b + (size_t)(rb ^ 1) * NB * KSZ;
                const int n_a = n0 + lrow;
                const __hip_bfloat16* a0 = h1r + (size_t)n_a * HID + krow;
                const __hip_bfloat16* a1 = h1r + (size_t)(n_a + 16) * HID + krow;
                const __hip_bfloat16* g0 = h2r + (size_t)n_a * KSZ + krow;
                const __hip_bfloat16* g1 = h2r + (size_t)(n_a + 16) * KSZ + krow;
                f32x4 acc0 = {0.f, 0.f, 0.f, 0.f}, acc1 = {0.f, 0.f, 0.f, 0.f};
                #pragma unroll
                for (int kk = 0; kk < 16; ++kk) {
                    acc0 = MFMA_BF16(LD8(a0 + kk * 32), wf[kk], acc0);
                    acc1 = MFMA_BF16(LD8(a1 + kk * 32), wf[kk], acc1);
                }
                #pragma unroll
                for (int kk = 16; kk < 20; ++kk) {
                    acc0 = MFMA_BF16(LD8(g0 + (kk - 16) * 32), wf[kk], acc0);
                    acc1 = MFMA_BF16(LD8(g1 + (kk - 16) * 32), wf[kk], acc1);
                }
                const int rbase = (lane >> 4) * 4;
                #pragma unroll
                for (int r = 0; r < 4; ++r) {
                    gl[w][rbase + r][lrow] = acc0[r];
                    gl[w][16 + rbase + r][lrow] = acc1[r];
                }
                __syncthreads();
                #pragma unroll
                for (int it = 0; it < 2; ++it) {
                    const int idx = tid + it * 256;
                    const int nl = idx >> 4, oo = idx & 15;
                    const int oc = og * 16 + oo;
                    const float iv = gl[0][nl][oo] + bi;
                    const float fv = gl[1][nl][oo] + bf_;
                    const float gv = gl[2][nl][oo] + bg;
                    const float ov = gl[3][nl][oo] + bo;
                    const int nn = n0 + nl;
                    const float cold = c2[nn * KSZ + oc];
                    const float cn = sig_(fv) * cold + sig_(iv) * tanh_fast(gv);
                    const float hn = sig_(ov) * tanh_fast(cn);
                    c2[nn * KSZ + oc] = cn;
                    h2w[nn * KSZ + oc] = __float2bfloat16(hn);
                    h2_all[((size_t)s2 * NB + nn) * KSZ + oc] = hn;
                }
            }
            if (i < L_SEQ) gbar_grp(gb, GRP_BLKS * (i + 1));
        }
    } else {
        // ================= gates1 =================
        const int bid2 = blockIdx.x - 32;
        const int grp = bid2 >> 5;
        int* gb = bar + grp * 64;
        const int n0 = grp * 32;
        const int og = bid2 & 31;
        const int col = w * 512 + og * 16 + lrow;
        const __hip_bfloat16* brow = Wc1 + (size_t)col * KK1 + krow;
        bf16x8 wf[24];                            // 96 VGPRs, persistent
        #pragma unroll
        for (int kk = 0; kk < 24; ++kk) wf[kk] = LD8(brow + kk * 32);
        const int oc_b = og * 16 + (tid & 15);
        const float bi = bb1[oc_b],         bf_ = bb1[512 + oc_b];
        const float bg = bb1[1024 + oc_b],  bo  = bb1[1536 + oc_b];
        for (int i = 0; i <= L_SEQ; ++i) {
            if (i < L_SEQ) {
                const int rb = i & 1;
                const __hip_bfloat16* h1r = h1b + (size_t)rb * NB * HID;
                __hip_bfloat16* h1w = h1b + (size_t)(rb ^ 1) * NB * HID;
                const int n_a = n0 + lrow;
                const __hip_bfloat16* e0 = ce_b + ((size_t)i * NB + n_a) * EMB + krow;
                const __hip_bfloat16* e1 = ce_b + ((size_t)i * NB + n_a + 16) * EMB + krow;
                const __hip_bfloat16* x0 = ctx1_b + ((size_t)i * NB + n_a) * VSZ + krow;
                const __hip_bfloat16* x1 = ctx1_b + ((size_t)i * NB + n_a + 16) * VSZ + krow;
                const __hip_bfloat16* a0 = h1r + (size_t)n_a * HID + krow;
                const __hip_bfloat16* a1 = h1r + (size_t)(n_a + 16) * HID + krow;
                f32x4 acc0 = {0.f, 0.f, 0.f, 0.f}, acc1 = {0.f, 0.f, 0.f, 0.f};
                #pragma unroll
                for (int kk = 0; kk < 4; ++kk) {
                    acc0 = MFMA_BF16(LD8(e0 + kk * 32), wf[kk], acc0);
                    acc1 = MFMA_BF16(LD8(e1 + kk * 32), wf[kk], acc1);
                }
                #pragma unroll
                for (int kk = 4; kk < 8; ++kk) {
                    acc0 = MFMA_BF16(LD8(x0 + (kk - 4) * 32), wf[kk], acc0);
                    acc1 = MFMA_BF16(LD8(x1 + (kk - 4) * 32), wf[kk], acc1);
                }
                #pragma unroll
                for (int kk = 8; kk < 24; ++kk) {
                    acc0 = MFMA_BF16(LD8(a0 + (kk - 8) * 32), wf[kk], acc0);
                    acc1 = MFMA_BF16(LD8(a1 + (kk - 8) * 32), wf[kk], acc1);
                }
                const int rbase = (lane >> 4) * 4;
                #pragma unroll
                for (int r = 0; r < 4; ++r) {
                    gl[w][rbase + r][lrow] = acc0[r];
                    gl[w][16 + rbase + r][lrow] = acc1[r];
                }
                __syncthreads();
                #pragma unroll
                for (int it = 0; it < 2; ++it) {
                    const int idx = tid + it * 256;
                    const int nl = idx >> 4, oo = idx & 15;
                    const int oc = og * 16 + oo;
                    const float iv = gl[0][nl][oo] + bi;
                    const float fv = gl[1][nl][oo] + bf_;
                    const float gv = gl[2][nl][oo] + bg;
                    const float ov = gl[3][nl][oo] + bo;
                    const int nn = n0 + nl;
                    const float cold = c1[nn * HID + oc];
                    const float cn = sig_(fv) * cold + sig_(iv) * tanh_fast(gv);
                    const float hn = sig_(ov) * tanh_fast(cn);
                    c1[nn * HID + oc] = cn;
                    h1w[nn * HID + oc] = __float2bfloat16(hn);
                }
            }
            if (i < L_SEQ) gbar_grp(gb, GRP_BLKS * (i + 1));
        }
    }
}

// ---------------- out = hardtanh([h2,ctx2]@Wfc.T+bfc); pred = out@emb.T+b_out -
__global__ __launch_bounds__(256) void outpred_kernel(
    const float* __restrict__ h2_all, const float* __restrict__ ctx2,
    const float* __restrict__ Wfc, const float* __restrict__ bfc,
    const float* __restrict__ emb, const float* __restrict__ b_out,
    float* __restrict__ out)
{
    __shared__ float xs[2][256];
    __shared__ float os[2][EMB];
    const int tid = threadIdx.x;
    const int r0 = blockIdx.x * 2;
    const int sub = tid >> 7, lane = tid & 127;
    const int r = r0 + sub;                               // r = s*NB + n
    xs[sub][lane] = h2_all[(size_t)r * KSZ + lane];
    xs[sub][128 + lane] = ctx2[(size_t)r * VSZ + lane];
    __syncthreads();
    const float* wr = Wfc + (size_t)lane * 256;
    float acc = bfc[lane];
    #pragma unroll 8
    for (int k = 0; k < 256; k += 4) {
        const float4 w4 = *(const float4*)&wr[k];
        const float4 x4 = *(const float4*)&xs[sub][k];
        acc += w4.x * x4.x + w4.y * x4.y + w4.z * x4.z + w4.w * x4.w;
    }
    acc = fminf(1.0f, fmaxf(-1.0f, acc));
    os[sub][lane] = acc;
    __syncthreads();
    if (lane < VOCAB) {
        const float* er = emb + (size_t)lane * EMB;
        float a = b_out[lane];
        #pragma unroll 8
        for (int e = 0; e < EMB; e += 4) {
            const float4 e4 = *(const float4*)&er[e];
            const float4 x4 = *(const float4*)&os[sub][e];
            a += e4.x * x4.x + e4.y * x4.y + e4.z * x4.z + e4.w * x4.w;
        }
        const int s = r >> 7, nn = r & 127;
        out[((size_t)nn * L_SEQ + s) * VOCAB + lane] = a;
    }
}

extern "C" void kernel_launch(void* const* d_in, const int* in_sizes, int n_in,
                              void* d_out, int out_size, void* d_ws, size_t ws_size,
                              hipStream_t stream)
{
    (void)in_sizes; (void)n_in; (void)out_size; (void)ws_size;
    const float* key_proj = (const float*)d_in[0];
    const float* values   = (const float*)d_in[1];
    const int*   rlen     = (const int*)d_in[2];
    const int*   text     = (const int*)d_in[3];
    const float* emb      = (const float*)d_in[4];
    const float* Wq    = (const float*)d_in[5];
    const float* bq    = (const float*)d_in[6];
    const float* Wih1  = (const float*)d_in[7];
    const float* Whh1  = (const float*)d_in[8];
    const float* bih1  = (const float*)d_in[9];
    const float* bhh1  = (const float*)d_in[10];
    const float* Wih2  = (const float*)d_in[11];
    const float* Whh2  = (const float*)d_in[12];
    const float* bih2  = (const float*)d_in[13];
    const float* bhh2  = (const float*)d_in[14];
    const float* Wfc   = (const float*)d_in[15];
    const float* bfc   = (const float*)d_in[16];
    const float* b_out = (const float*)d_in[17];
    float* out = (float*)d_out;

    char* p = (char*)d_ws;
    auto take = [&p](size_t bytes) -> char* {
        char* r = p;
        p += (bytes + 255) & ~((size_t)255);
        return r;
    };
    float* ce_f  = (float*)take((size_t)L_SEQ * NB * EMB * 4);
    __hip_bfloat16* ce_b  = (__hip_bfloat16*)take((size_t)L_SEQ * NB * EMB * 2);
    __hip_bfloat16* ctx_b = (__hip_bfloat16*)take((size_t)L_SEQ * NB * VSZ * 2);
    float* ctx_f  = (float*)take((size_t)L_SEQ * NB * VSZ * 4);
    float* qbuf   = (float*)take((size_t)L_SEQ * NB * KSZ * 4);
    float* h2_all = (float*)take((size_t)L_SEQ * NB * KSZ * 4);
    __hip_bfloat16* Wc1 = (__hip_bfloat16*)take((size_t)G1 * KK1 * 2);
    __hip_bfloat16* Wc2 = (__hip_bfloat16*)take((size_t)G2 * KK2 * 2);
    float* bb1 = (float*)take(G1 * 4);
    float* bb2 = (float*)take(G2 * 4);
    __hip_bfloat16* h1b = (__hip_bfloat16*)take((size_t)2 * NB * HID * 2);
    __hip_bfloat16* h2b = (__hip_bfloat16*)take((size_t)2 * NB * KSZ * 2);
    float* c1 = (float*)take((size_t)NB * HID * 4);
    float* c2 = (float*)take((size_t)NB * KSZ * 4);
    int* bar = (int*)take(1024);

    prep_kernel<<<6144, 256, 0, stream>>>(Wih1, Whh1, bih1, bhh1, Wih2, Whh2,
                                          bih2, bhh2, Wc1, Wc2, bb1, bb2,
                                          h1b, h2b, c1, c2, bar);
    ce_gather<<<12800, 256, 0, stream>>>(text, emb, ce_f, ce_b);
    qproj_kernel<<<12800, 256, 0, stream>>>(ce_f, Wq, bq, qbuf);
    attn_kernel<<<512, 256, 0, stream>>>(qbuf, key_proj, values, rlen, ctx_f, ctx_b);
    scan_persist<<<NBLK, 256, 0, stream>>>(Wc1, Wc2, bb1, bb2, ce_b, ctx_b,
                                           h1b, h2b, c1, c2, h2_all, bar);
    qproj_kernel<<<12800, 256, 0, stream>>>(h2_all, Wq, bq, qbuf);
    attn_kernel<<<512, 256, 0, stream>>>(qbuf, key_proj, values, rlen, ctx_f, ctx_b);
    outpred_kernel<<<12800, 256, 0, stream>>>(h2_all, ctx_f, Wfc, bfc, emb, b_out, out);
}

// Round 4
// 3770.469 us; speedup vs baseline: 1.5581x; 1.5581x over previous
//
#include <hip/hip_runtime.h>
#include <hip/hip_bf16.h>
#include <math.h>

#define T_LEN 1024
#define NB    128
#define L_SEQ 200
#define EMB   128
#define KSZ   128
#define VSZ   128
#define HID   512
#define G1    2048   // 4*HID
#define G2    512    // 4*KSZ
#define VOCAB 34
#define KK1   768    // EMB + VSZ + HID   (combined K for LSTM1 gates)
#define KK2   640    // HID + KSZ         (combined K for LSTM2 gates)
#define TT    64     // attention t-tile
#define NBLK  160    // persistent scan blocks (32 gates2 + 128 gates1)
#define GRP_BLKS 40  // per n-group: 8 gates2 + 32 gates1

typedef __attribute__((ext_vector_type(8))) short bf16x8;  // 8 bf16 = 4 VGPRs
typedef __attribute__((ext_vector_type(4))) float f32x4;

__device__ __forceinline__ float sig_(float x) { return 1.0f / (1.0f + __expf(-x)); }
__device__ __forceinline__ float tanh_fast(float x) {
    return 1.0f - 2.0f / (__expf(2.0f * x) + 1.0f);   // inf-safe at both ends
}

__device__ __forceinline__ f32x4 MFMA_BF16(bf16x8 a, bf16x8 b, f32x4 c) {
    return __builtin_amdgcn_mfma_f32_16x16x32_bf16(a, b, c, 0, 0, 0);
}
__device__ __forceinline__ bf16x8 LD8(const __hip_bfloat16* p) {
    return *(const bf16x8*)p;
}
// Coherent (cross-XCD) exchange ops: relaxed agent-scope atomics carry per-access
// cache-bypass (sc1) on gfx950 — no wbl2/inv fences, unrelated cached data stays hot.
__device__ __forceinline__ bf16x8 LD8CC(const unsigned int* p) {
    union { bf16x8 v; unsigned long long q[2]; } u;
    unsigned long long* pp = (unsigned long long*)p;
    u.q[0] = __hip_atomic_load(pp,     __ATOMIC_RELAXED, __HIP_MEMORY_SCOPE_AGENT);
    u.q[1] = __hip_atomic_load(pp + 1, __ATOMIC_RELAXED, __HIP_MEMORY_SCOPE_AGENT);
    return u.v;
}
__device__ __forceinline__ void ST4CC(unsigned int* p, unsigned int v) {
    __hip_atomic_store(p, v, __ATOMIC_RELAXED, __HIP_MEMORY_SCOPE_AGENT);
}

// Group barrier, fence-free: own stores drained to the coherence point via
// vmcnt(0), then relaxed monotonic counter. Timeout escape hatch: a residency
// failure yields a wrong-but-measurable run, never a hang.
__device__ __forceinline__ void gbar_grp(int* bar, int tgt) {
    asm volatile("s_waitcnt vmcnt(0)" ::: "memory");
    __syncthreads();
    if (threadIdx.x == 0) {
        __hip_atomic_fetch_add(bar, 1, __ATOMIC_RELAXED, __HIP_MEMORY_SCOPE_AGENT);
        const long long t0 = __builtin_amdgcn_s_memrealtime();
        while (__hip_atomic_load(bar, __ATOMIC_RELAXED, __HIP_MEMORY_SCOPE_AGENT) < tgt) {
            __builtin_amdgcn_s_sleep(2);
            if (__builtin_amdgcn_s_memrealtime() - t0 > 2000000LL) break;  // ~20-80ms
        }
    }
    __syncthreads();
}

// ---------------- prep: combined bf16 weights, biases, zeroed states ----------
__global__ __launch_bounds__(256) void prep_kernel(
    const float* __restrict__ Wih1, const float* __restrict__ Whh1,
    const float* __restrict__ bih1, const float* __restrict__ bhh1,
    const float* __restrict__ Wih2, const float* __restrict__ Whh2,
    const float* __restrict__ bih2, const float* __restrict__ bhh2,
    __hip_bfloat16* __restrict__ Wc1, __hip_bfloat16* __restrict__ Wc2,
    float* __restrict__ bb1, float* __restrict__ bb2,
    unsigned int* __restrict__ h1x, unsigned int* __restrict__ h2x,
    int* __restrict__ bar)
{
    const int gid = blockIdx.x * 256 + threadIdx.x;
    if (gid < G1 * KK1) {
        const int o = gid / KK1, k = gid - o * KK1;
        const float v = (k < 256) ? Wih1[o * 256 + k] : Whh1[o * 512 + (k - 256)];
        Wc1[gid] = __float2bfloat16(v);
    }
    if (gid < G2 * KK2) {
        const int o = gid / KK2, k = gid - o * KK2;
        const float v = (k < 512) ? Wih2[o * 512 + k] : Whh2[o * 128 + (k - 512)];
        Wc2[gid] = __float2bfloat16(v);
    }
    if (gid < G1) bb1[gid] = bih1[gid] + bhh1[gid];
    if (gid < G2) bb2[gid] = bih2[gid] + bhh2[gid];
    if (gid < 2 * NB * HID / 2) h1x[gid] = 0u;    // both parities = h(-1) = 0
    if (gid < 2 * NB * KSZ / 2) h2x[gid] = 0u;
    if (gid < 256) bar[gid] = 0;                  // 4 group counters, 256B apart
}

// ---------------- teacher-forced embedding gather -----------------------------
__global__ __launch_bounds__(256) void ce_gather(
    const int* __restrict__ text, const float* __restrict__ emb,
    float* __restrict__ ce_f, __hip_bfloat16* __restrict__ ce_b)
{
    const int idx = blockIdx.x * 256 + threadIdx.x;   // exact: L*N*128
    const int k = idx & 127;
    const int rn = idx >> 7;
    const int nn = rn & 127;
    const int s = rn >> 7;
    if (s >= L_SEQ) return;
    const int tok = (s == 0) ? 0 : text[nn * L_SEQ + (s - 1)];
    const float v = emb[(size_t)tok * EMB + k];
    ce_f[idx] = v;
    ce_b[idx] = __float2bfloat16(v);
}

// ---------------- q = src @ Wq.T + bq  (rows = L*N) ---------------------------
__global__ __launch_bounds__(256) void qproj_kernel(
    const float* __restrict__ src, const float* __restrict__ Wq,
    const float* __restrict__ bq, float* __restrict__ dst)
{
    __shared__ float xs[2][KSZ];
    const int tid = threadIdx.x;
    const int r0 = blockIdx.x * 2;
    xs[tid >> 7][tid & 127] = src[(size_t)(r0 + (tid >> 7)) * KSZ + (tid & 127)];
    __syncthreads();
    const int sub = tid >> 7, o = tid & 127;
    const float* wr = Wq + (size_t)o * KSZ;
    float acc = bq[o];
    #pragma unroll 8
    for (int k = 0; k < KSZ; k += 4) {
        const float4 w4 = *(const float4*)&wr[k];
        const float4 x4 = *(const float4*)&xs[sub][k];
        acc += w4.x * x4.x + w4.y * x4.y + w4.z * x4.z + w4.w * x4.w;
    }
    dst[(size_t)(r0 + sub) * KSZ + o] = acc;
}

// ---------------- flash attention: ctx = softmax(q.K^T) @ V -------------------
__global__ __launch_bounds__(256) void attn_kernel(
    const float* __restrict__ q,      // [L][N][KSZ]
    const float* __restrict__ key,    // [T][N][KSZ]
    const float* __restrict__ values, // [T][N][VSZ]
    const int* __restrict__ rlen,
    float* __restrict__ ctx_f,        // [L][N][VSZ]
    __hip_bfloat16* __restrict__ ctx_b)
{
    __shared__ __align__(16) float q_s[52][128];   // rows 50,51 zeroed
    __shared__ __align__(16) float Kt[TT][129];    // +1 pad: conflict-free col reads
    __shared__ __align__(16) float Vt[TT][129];
    __shared__ __align__(16) float es[52][68];     // row stride 272B (16B mult)
    __shared__ float mm[52], ss[52], al[52];
    const int tid = threadIdx.x;
    const int n = blockIdx.x >> 2;
    const int l0 = (blockIdx.x & 3) * 50;
    const int len = rlen[n];

    for (int idx = tid; idx < 52 * 128; idx += 256) {
        const int l = idx >> 7, k = idx & 127;
        q_s[l][k] = (l < 50) ? q[((size_t)(l0 + l) * NB + n) * KSZ + k] : 0.0f;
    }
    for (int l = tid; l < 52; l += 256) { mm[l] = -3.0e38f; ss[l] = 0.0f; }
    float acc[25];
    #pragma unroll
    for (int j = 0; j < 25; ++j) acc[j] = 0.0f;
    __syncthreads();

    const int lg = tid >> 6, lane = tid & 63;
    const int vv = tid & 127, hh = tid >> 7;
    const int nt = (len + TT - 1) / TT;

    for (int tt = 0; tt < nt; ++tt) {
        const int tb = tt * TT;
        const int valid = min(TT, len - tb);
        #pragma unroll
        for (int it = 0; it < 8; ++it) {
            const int idx4 = tid + it * 256;          // 2048 float4 slots
            const int r = idx4 >> 5, c4 = (idx4 & 31) * 4;
            float4 kq = make_float4(0.f, 0.f, 0.f, 0.f);
            float4 vq = make_float4(0.f, 0.f, 0.f, 0.f);
            if (r < valid) {
                const size_t base = ((size_t)(tb + r) * NB + n) * 128 + c4;
                kq = *(const float4*)&key[base];
                vq = *(const float4*)&values[base];
            }
            Kt[r][c4 + 0] = kq.x; Kt[r][c4 + 1] = kq.y;
            Kt[r][c4 + 2] = kq.z; Kt[r][c4 + 3] = kq.w;
            Vt[r][c4 + 0] = vq.x; Vt[r][c4 + 1] = vq.y;
            Vt[r][c4 + 2] = vq.z; Vt[r][c4 + 3] = vq.w;
        }
        __syncthreads();
        {
            float e[13];
            #pragma unroll
            for (int j = 0; j < 13; ++j) e[j] = 0.0f;
            for (int k4 = 0; k4 < 128; k4 += 4) {
                const float c0 = Kt[lane][k4 + 0], c1 = Kt[lane][k4 + 1];
                const float c2 = Kt[lane][k4 + 2], c3 = Kt[lane][k4 + 3];
                #pragma unroll
                for (int j = 0; j < 13; ++j) {
                    const float4 q4 = *(const float4*)&q_s[lg * 13 + j][k4];
                    e[j] += c0 * q4.x + c1 * q4.y + c2 * q4.z + c3 * q4.w;
                }
            }
            #pragma unroll
            for (int j = 0; j < 13; ++j) {
                const int l = lg * 13 + j;
                float ev = (lane < valid) ? e[j] : -3.0e38f;
                #pragma unroll
                for (int off = 32; off; off >>= 1) ev = fmaxf(ev, __shfl_xor(ev, off, 64));
                const float mold = mm[l];
                const float mnew = fmaxf(mold, ev);
                const float p = (lane < valid) ? __expf(e[j] - mnew) : 0.0f;
                es[l][lane] = p;
                float ps = p;
                #pragma unroll
                for (int off = 32; off; off >>= 1) ps += __shfl_xor(ps, off, 64);
                if (lane == 0) {
                    const float a = __expf(mold - mnew);   // 0 on first tile
                    al[l] = a;
                    ss[l] = ss[l] * a + ps;
                    mm[l] = mnew;
                }
            }
        }
        __syncthreads();
        #pragma unroll
        for (int j = 0; j < 25; ++j) {
            const int l = hh + 2 * j;
            float a = acc[j] * al[l];
            #pragma unroll 4
            for (int t4 = 0; t4 < TT; t4 += 4) {
                const float4 p4 = *(const float4*)&es[l][t4];
                a += p4.x * Vt[t4 + 0][vv] + p4.y * Vt[t4 + 1][vv]
                   + p4.z * Vt[t4 + 2][vv] + p4.w * Vt[t4 + 3][vv];
            }
            acc[j] = a;
        }
        __syncthreads();
    }
    #pragma unroll
    for (int j = 0; j < 25; ++j) {
        const int l = hh + 2 * j;
        const float r = acc[j] / ss[l];
        const size_t o = ((size_t)(l0 + l) * NB + n) * VSZ + vv;
        ctx_f[o] = r;
        ctx_b[o] = __float2bfloat16(r);
    }
}

// ---------------- persistent scan, fence-free -----------------------------------
// 4 n-groups x (8 gates2 + 32 gates1) blocks. Waves split K (not gates): wave w
// computes partial gate-sums for all 4 gates over its K-quarter; epilogue sums
// partials in LDS. c-state lives in registers (block owns its tile for all 200
// steps). h1/h2 cross-block exchange via relaxed agent atomics (u32 bf16-pairs).
__global__ __launch_bounds__(256) void scan_persist(
    const __hip_bfloat16* __restrict__ Wc1, const __hip_bfloat16* __restrict__ Wc2,
    const float* __restrict__ bb1, const float* __restrict__ bb2,
    const __hip_bfloat16* __restrict__ ce_b, const __hip_bfloat16* __restrict__ ctx1_b,
    unsigned int* __restrict__ h1x, unsigned int* __restrict__ h2x,
    float* __restrict__ h2_all, int* __restrict__ bar)
{
    const int tid = threadIdx.x;
    const int w = tid >> 6;               // wave = K-slice index
    const int lane = tid & 63;
    const int lrow = lane & 15;
    const int krow = (lane >> 4) * 8;
    __shared__ float gl[4][32][65];       // [k-wave][sample][gate*16+ch] partials
    const int nl = tid >> 3, op = tid & 7;   // epilogue: (sample, ch-pair)

    if (blockIdx.x < 32) {
        // ================= gates2: h2(s) = LSTM2(h1(s), h2(s-1)) =================
        const int grp = blockIdx.x >> 3;
        int* gb = bar + grp * 64;
        const int n0 = grp * 32;
        const int og = blockIdx.x & 7;
        const int wbase = w * 160;        // K in [0,640) = h1[0:512] | h2[512:640]
        bf16x8 wf[20];                    // 80 VGPRs persistent weights
        #pragma unroll
        for (int t = 0; t < 4; ++t)
            #pragma unroll
            for (int j = 0; j < 5; ++j)
                wf[t * 5 + j] = LD8(Wc2 + (size_t)(t * 128 + og * 16 + lrow) * KK2
                                        + wbase + j * 32 + krow);
        const int oc = og * 16 + 2 * op;
        float bia[4][2];
        #pragma unroll
        for (int g = 0; g < 4; ++g) {
            bia[g][0] = bb2[g * 128 + oc];
            bia[g][1] = bb2[g * 128 + oc + 1];
        }
        float cst0 = 0.0f, cst1 = 0.0f;   // register-resident c2
        for (int i = 0; i <= L_SEQ; ++i) {
            if (i >= 1) {
                const int s2 = i - 1;
                const int rb = i & 1;
                const unsigned int* h1r = h1x + rb * (NB * HID / 2);
                const unsigned int* h2r = h2x + rb * (NB * KSZ / 2);
                unsigned int* h2w = h2x + (rb ^ 1) * (NB * KSZ / 2);
                f32x4 acc0[4] = {{0,0,0,0},{0,0,0,0},{0,0,0,0},{0,0,0,0}};
                f32x4 acc1[4] = {{0,0,0,0},{0,0,0,0},{0,0,0,0},{0,0,0,0}};
                #pragma unroll
                for (int j = 0; j < 5; ++j) {
                    const int kg = wbase + j * 32 + krow;
                    bf16x8 a0, a1;
                    if (kg < 512) {
                        a0 = LD8CC(h1r + (n0 + lrow) * (HID / 2) + kg / 2);
                        a1 = LD8CC(h1r + (n0 + lrow + 16) * (HID / 2) + kg / 2);
                    } else {
                        a0 = LD8CC(h2r + (n0 + lrow) * (KSZ / 2) + (kg - 512) / 2);
                        a1 = LD8CC(h2r + (n0 + lrow + 16) * (KSZ / 2) + (kg - 512) / 2);
                    }
                    #pragma unroll
                    for (int t = 0; t < 4; ++t) {
                        acc0[t] = MFMA_BF16(a0, wf[t * 5 + j], acc0[t]);
                        acc1[t] = MFMA_BF16(a1, wf[t * 5 + j], acc1[t]);
                    }
                }
                const int rbase = (lane >> 4) * 4;
                #pragma unroll
                for (int t = 0; t < 4; ++t)
                    #pragma unroll
                    for (int r = 0; r < 4; ++r) {
                        gl[w][rbase + r][t * 16 + lrow] = acc0[t][r];
                        gl[w][16 + rbase + r][t * 16 + lrow] = acc1[t][r];
                    }
                __syncthreads();
                float hv0, hv1;
                {
                    float sg[4][2];
                    #pragma unroll
                    for (int g = 0; g < 4; ++g)
                        #pragma unroll
                        for (int cc = 0; cc < 2; ++cc)
                            sg[g][cc] = gl[0][nl][g * 16 + 2 * op + cc]
                                      + gl[1][nl][g * 16 + 2 * op + cc]
                                      + gl[2][nl][g * 16 + 2 * op + cc]
                                      + gl[3][nl][g * 16 + 2 * op + cc] + bia[g][cc];
                    const float cn0 = sig_(sg[1][0]) * cst0 + sig_(sg[0][0]) * tanh_fast(sg[2][0]);
                    const float cn1 = sig_(sg[1][1]) * cst1 + sig_(sg[0][1]) * tanh_fast(sg[2][1]);
                    hv0 = sig_(sg[3][0]) * tanh_fast(cn0);
                    hv1 = sig_(sg[3][1]) * tanh_fast(cn1);
                    cst0 = cn0; cst1 = cn1;
                }
                const int nn = n0 + nl;
                union { unsigned int u; __hip_bfloat16 b[2]; } pk;
                pk.b[0] = __float2bfloat16(hv0);
                pk.b[1] = __float2bfloat16(hv1);
                ST4CC(h2w + nn * (KSZ / 2) + oc / 2, pk.u);
                *(float2*)&h2_all[((size_t)s2 * NB + nn) * KSZ + oc] = make_float2(hv0, hv1);
            }
            if (i < L_SEQ) gbar_grp(gb, GRP_BLKS * (i + 1));
        }
    } else {
        // ================= gates1: h1(i) = LSTM1([ce,ctx,h1(i-1)]) ==============
        const int bid2 = blockIdx.x - 32;
        const int grp = bid2 >> 5;
        int* gb = bar + grp * 64;
        const int n0 = grp * 32;
        const int og = bid2 & 31;
        const int wbase = w * 192;        // K in [0,768) = ce[0:128]|ctx[128:256]|h1[256:768]
        bf16x8 wf[24];                    // 96 VGPRs persistent weights
        #pragma unroll
        for (int t = 0; t < 4; ++t)
            #pragma unroll
            for (int j = 0; j < 6; ++j)
                wf[t * 6 + j] = LD8(Wc1 + (size_t)(t * 512 + og * 16 + lrow) * KK1
                                        + wbase + j * 32 + krow);
        const int oc = og * 16 + 2 * op;
        float bia[4][2];
        #pragma unroll
        for (int g = 0; g < 4; ++g) {
            bia[g][0] = bb1[g * 512 + oc];
            bia[g][1] = bb1[g * 512 + oc + 1];
        }
        float cst0 = 0.0f, cst1 = 0.0f;   // register-resident c1
        for (int i = 0; i < L_SEQ; ++i) {
            const int rb = i & 1;
            const unsigned int* h1r = h1x + rb * (NB * HID / 2);
            unsigned int* h1w = h1x + (rb ^ 1) * (NB * HID / 2);
            f32x4 acc0[4] = {{0,0,0,0},{0,0,0,0},{0,0,0,0},{0,0,0,0}};
            f32x4 acc1[4] = {{0,0,0,0},{0,0,0,0},{0,0,0,0},{0,0,0,0}};
            #pragma unroll
            for (int j = 0; j < 6; ++j) {
                const int kg = wbase + j * 32 + krow;
                bf16x8 a0, a1;
                if (kg < 128) {
                    a0 = LD8(ce_b + ((size_t)i * NB + n0 + lrow) * EMB + kg);
                    a1 = LD8(ce_b + ((size_t)i * NB + n0 + lrow + 16) * EMB + kg);
                } else if (kg < 256) {
                    a0 = LD8(ctx1_b + ((size_t)i * NB + n0 + lrow) * VSZ + kg - 128);
                    a1 = LD8(ctx1_b + ((size_t)i * NB + n0 + lrow + 16) * VSZ + kg - 128);
                } else {
                    a0 = LD8CC(h1r + (n0 + lrow) * (HID / 2) + (kg - 256) / 2);
                    a1 = LD8CC(h1r + (n0 + lrow + 16) * (HID / 2) + (kg - 256) / 2);
                }
                #pragma unroll
                for (int t = 0; t < 4; ++t) {
                    acc0[t] = MFMA_BF16(a0, wf[t * 6 + j], acc0[t]);
                    acc1[t] = MFMA_BF16(a1, wf[t * 6 + j], acc1[t]);
                }
            }
            const int rbase = (lane >> 4) * 4;
            #pragma unroll
            for (int t = 0; t < 4; ++t)
                #pragma unroll
                for (int r = 0; r < 4; ++r) {
                    gl[w][rbase + r][t * 16 + lrow] = acc0[t][r];
                    gl[w][16 + rbase + r][t * 16 + lrow] = acc1[t][r];
                }
            __syncthreads();
            float hv0, hv1;
            {
                float sg[4][2];
                #pragma unroll
                for (int g = 0; g < 4; ++g)
                    #pragma unroll
                    for (int cc = 0; cc < 2; ++cc)
                        sg[g][cc] = gl[0][nl][g * 16 + 2 * op + cc]
                                  + gl[1][nl][g * 16 + 2 * op + cc]
                                  + gl[2][nl][g * 16 + 2 * op + cc]
                                  + gl[3][nl][g * 16 + 2 * op + cc] + bia[g][cc];
                const float cn0 = sig_(sg[1][0]) * cst0 + sig_(sg[0][0]) * tanh_fast(sg[2][0]);
                const float cn1 = sig_(sg[1][1]) * cst1 + sig_(sg[0][1]) * tanh_fast(sg[2][1]);
                hv0 = sig_(sg[3][0]) * tanh_fast(cn0);
                hv1 = sig_(sg[3][1]) * tanh_fast(cn1);
                cst0 = cn0; cst1 = cn1;
            }
            union { unsigned int u; __hip_bfloat16 b[2]; } pk;
            pk.b[0] = __float2bfloat16(hv0);
            pk.b[1] = __float2bfloat16(hv1);
            ST4CC(h1w + (n0 + nl) * (HID / 2) + oc / 2, pk.u);
            gbar_grp(gb, GRP_BLKS * (i + 1));
        }
    }
}

// ---------------- out = hardtanh([h2,ctx2]@Wfc.T+bfc); pred = out@emb.T+b_out -
__global__ __launch_bounds__(256) void outpred_kernel(
    const float* __restrict__ h2_all, const float* __restrict__ ctx2,
    const float* __restrict__ Wfc, const float* __restrict__ bfc,
    const float* __restrict__ emb, const float* __restrict__ b_out,
    float* __restrict__ out)
{
    __shared__ float xs[2][256];
    __shared__ float os[2][EMB];
    const int tid = threadIdx.x;
    const int r0 = blockIdx.x * 2;
    const int sub = tid >> 7, lane = tid & 127;
    const int r = r0 + sub;                               // r = s*NB + n
    xs[sub][lane] = h2_all[(size_t)r * KSZ + lane];
    xs[sub][128 + lane] = ctx2[(size_t)r * VSZ + lane];
    __syncthreads();
    const float* wr = Wfc + (size_t)lane * 256;
    float acc = bfc[lane];
    #pragma unroll 8
    for (int k = 0; k < 256; k += 4) {
        const float4 w4 = *(const float4*)&wr[k];
        const float4 x4 = *(const float4*)&xs[sub][k];
        acc += w4.x * x4.x + w4.y * x4.y + w4.z * x4.z + w4.w * x4.w;
    }
    acc = fminf(1.0f, fmaxf(-1.0f, acc));
    os[sub][lane] = acc;
    __syncthreads();
    if (lane < VOCAB) {
        const float* er = emb + (size_t)lane * EMB;
        float a = b_out[lane];
        #pragma unroll 8
        for (int e = 0; e < EMB; e += 4) {
            const float4 e4 = *(const float4*)&er[e];
            const float4 x4 = *(const float4*)&os[sub][e];
            a += e4.x * x4.x + e4.y * x4.y + e4.z * x4.z + e4.w * x4.w;
        }
        const int s = r >> 7, nn = r & 127;
        out[((size_t)nn * L_SEQ + s) * VOCAB + lane] = a;
    }
}

extern "C" void kernel_launch(void* const* d_in, const int* in_sizes, int n_in,
                              void* d_out, int out_size, void* d_ws, size_t ws_size,
                              hipStream_t stream)
{
    (void)in_sizes; (void)n_in; (void)out_size; (void)ws_size;
    const float* key_proj = (const float*)d_in[0];
    const float* values   = (const float*)d_in[1];
    const int*   rlen     = (const int*)d_in[2];
    const int*   text     = (const int*)d_in[3];
    const float* emb      = (const float*)d_in[4];
    const float* Wq    = (const float*)d_in[5];
    const float* bq    = (const float*)d_in[6];
    const float* Wih1  = (const float*)d_in[7];
    const float* Whh1  = (const float*)d_in[8];
    const float* bih1  = (const float*)d_in[9];
    const float* bhh1  = (const float*)d_in[10];
    const float* Wih2  = (const float*)d_in[11];
    const float* Whh2  = (const float*)d_in[12];
    const float* bih2  = (const float*)d_in[13];
    const float* bhh2  = (const float*)d_in[14];
    const float* Wfc   = (const float*)d_in[15];
    const float* bfc   = (const float*)d_in[16];
    const float* b_out = (const float*)d_in[17];
    float* out = (float*)d_out;

    char* p = (char*)d_ws;
    auto take = [&p](size_t bytes) -> char* {
        char* r = p;
        p += (bytes + 255) & ~((size_t)255);
        return r;
    };
    float* ce_f  = (float*)take((size_t)L_SEQ * NB * EMB * 4);
    __hip_bfloat16* ce_b  = (__hip_bfloat16*)take((size_t)L_SEQ * NB * EMB * 2);
    __hip_bfloat16* ctx_b = (__hip_bfloat16*)take((size_t)L_SEQ * NB * VSZ * 2);
    float* ctx_f  = (float*)take((size_t)L_SEQ * NB * VSZ * 4);
    float* qbuf   = (float*)take((size_t)L_SEQ * NB * KSZ * 4);
    float* h2_all = (float*)take((size_t)L_SEQ * NB * KSZ * 4);
    __hip_bfloat16* Wc1 = (__hip_bfloat16*)take((size_t)G1 * KK1 * 2);
    __hip_bfloat16* Wc2 = (__hip_bfloat16*)take((size_t)G2 * KK2 * 2);
    float* bb1 = (float*)take(G1 * 4);
    float* bb2 = (float*)take(G2 * 4);
    unsigned int* h1x = (unsigned int*)take((size_t)2 * NB * HID / 2 * 4);
    unsigned int* h2x = (unsigned int*)take((size_t)2 * NB * KSZ / 2 * 4);
    int* bar = (int*)take(1024);

    prep_kernel<<<6144, 256, 0, stream>>>(Wih1, Whh1, bih1, bhh1, Wih2, Whh2,
                                          bih2, bhh2, Wc1, Wc2, bb1, bb2,
                                          h1x, h2x, bar);
    ce_gather<<<12800, 256, 0, stream>>>(text, emb, ce_f, ce_b);
    qproj_kernel<<<12800, 256, 0, stream>>>(ce_f, Wq, bq, qbuf);
    attn_kernel<<<512, 256, 0, stream>>>(qbuf, key_proj, values, rlen, ctx_f, ctx_b);
    scan_persist<<<NBLK, 256, 0, stream>>>(Wc1, Wc2, bb1, bb2, ce_b, ctx_b,
                                           h1x, h2x, h2_all, bar);
    qproj_kernel<<<12800, 256, 0, stream>>>(h2_all, Wq, bq, qbuf);
    attn_kernel<<<512, 256, 0, stream>>>(qbuf, key_proj, values, rlen, ctx_f, ctx_b);
    outpred_kernel<<<12800, 256, 0, stream>>>(h2_all, ctx_f, Wfc, bfc, emb, b_out, out);
}

// Round 5
// 3454.678 us; speedup vs baseline: 1.7006x; 1.0914x over previous
//
#include <hip/hip_runtime.h>
#include <hip/hip_bf16.h>
#include <math.h>

#define T_LEN 1024
#define NB    128
#define L_SEQ 200
#define EMB   128
#define KSZ   128
#define VSZ   128
#define HID   512
#define G1    2048
#define G2    512
#define VOCAB 34
#define KK1   768    // EMB + VSZ + HID
#define KK2   640    // HID + KSZ
#define TT    64     // attention t-tile
#define NBLK  160    // 32 gates2 + 128 gates1

typedef __attribute__((ext_vector_type(8))) short bf16x8;
typedef __attribute__((ext_vector_type(4))) float f32x4;

__device__ __forceinline__ float sig_(float x) { return 1.0f / (1.0f + __expf(-x)); }
__device__ __forceinline__ float tanh_fast(float x) {
    return 1.0f - 2.0f / (__expf(2.0f * x) + 1.0f);
}
__device__ __forceinline__ f32x4 MFMA_BF16(bf16x8 a, bf16x8 b, f32x4 c) {
    return __builtin_amdgcn_mfma_f32_16x16x32_bf16(a, b, c, 0, 0, 0);
}
__device__ __forceinline__ bf16x8 LD8(const __hip_bfloat16* p) {
    return *(const bf16x8*)p;
}
// Coherent exchange: relaxed agent-scope atomics (per-access L2-bypass, no fences)
__device__ __forceinline__ bf16x8 LD8CC(const unsigned int* p) {
    union { bf16x8 v; unsigned long long q[2]; } u;
    unsigned long long* pp = (unsigned long long*)p;
    u.q[0] = __hip_atomic_load(pp,     __ATOMIC_RELAXED, __HIP_MEMORY_SCOPE_AGENT);
    u.q[1] = __hip_atomic_load(pp + 1, __ATOMIC_RELAXED, __HIP_MEMORY_SCOPE_AGENT);
    return u.v;
}
__device__ __forceinline__ void ST4CC(unsigned int* p, unsigned int v) {
    __hip_atomic_store(p, v, __ATOMIC_RELAXED, __HIP_MEMORY_SCOPE_AGENT);
}
__device__ __forceinline__ void CADD(int* p) {
    __hip_atomic_fetch_add(p, 1, __ATOMIC_RELAXED, __HIP_MEMORY_SCOPE_AGENT);
}
// Per-group counter block: slots (64-int = 256B apart): 0..3 = ctr1 subs
// (8 gates1 adders each), 4 = ctrR (gates2 loads-done), 5 = ctr2 (gates2 done).
// Spin: all 4 ctr1 subs >= t1 AND slot slotR >= tR. Timeout hatch: never hangs.
__device__ __forceinline__ void spinw(int* gb, int t1, int tR, int slotR) {
    const long long t0 = __builtin_amdgcn_s_memrealtime();
    for (;;) {
        const int a = __hip_atomic_load(gb +   0, __ATOMIC_RELAXED, __HIP_MEMORY_SCOPE_AGENT);
        const int b = __hip_atomic_load(gb +  64, __ATOMIC_RELAXED, __HIP_MEMORY_SCOPE_AGENT);
        const int c = __hip_atomic_load(gb + 128, __ATOMIC_RELAXED, __HIP_MEMORY_SCOPE_AGENT);
        const int d = __hip_atomic_load(gb + 192, __ATOMIC_RELAXED, __HIP_MEMORY_SCOPE_AGENT);
        const int r = __hip_atomic_load(gb + slotR * 64, __ATOMIC_RELAXED, __HIP_MEMORY_SCOPE_AGENT);
        if (a >= t1 && b >= t1 && c >= t1 && d >= t1 && r >= tR) return;
        __builtin_amdgcn_s_sleep(1);
        if (__builtin_amdgcn_s_memrealtime() - t0 > 2000000LL) return;
    }
}

// ---------------- prep ---------------------------------------------------------
__global__ __launch_bounds__(256) void prep_kernel(
    const float* __restrict__ Wih1, const float* __restrict__ Whh1,
    const float* __restrict__ bih1, const float* __restrict__ bhh1,
    const float* __restrict__ Wih2, const float* __restrict__ Whh2,
    const float* __restrict__ bih2, const float* __restrict__ bhh2,
    __hip_bfloat16* __restrict__ Wc1, __hip_bfloat16* __restrict__ Wc2,
    float* __restrict__ bb1, float* __restrict__ bb2,
    unsigned int* __restrict__ h1x, unsigned int* __restrict__ h2x,
    int* __restrict__ bar)
{
    const int gid = blockIdx.x * 256 + threadIdx.x;
    if (gid < G1 * KK1) {
        const int o = gid / KK1, k = gid - o * KK1;
        const float v = (k < 256) ? Wih1[o * 256 + k] : Whh1[o * 512 + (k - 256)];
        Wc1[gid] = __float2bfloat16(v);
    }
    if (gid < G2 * KK2) {
        const int o = gid / KK2, k = gid - o * KK2;
        const float v = (k < 512) ? Wih2[o * 512 + k] : Whh2[o * 128 + (k - 512)];
        Wc2[gid] = __float2bfloat16(v);
    }
    if (gid < G1) bb1[gid] = bih1[gid] + bhh1[gid];
    if (gid < G2) bb2[gid] = bih2[gid] + bhh2[gid];
    if (gid < 2 * NB * HID / 2) h1x[gid] = 0u;
    if (gid < 2 * NB * KSZ / 2) h2x[gid] = 0u;
    if (gid < 2048) bar[gid] = 0;
}

// ---------------- teacher-forced embedding gather ------------------------------
__global__ __launch_bounds__(256) void ce_gather(
    const int* __restrict__ text, const float* __restrict__ emb,
    float* __restrict__ ce_f, __hip_bfloat16* __restrict__ ce_b)
{
    const int idx = blockIdx.x * 256 + threadIdx.x;
    const int k = idx & 127;
    const int rn = idx >> 7;
    const int nn = rn & 127;
    const int s = rn >> 7;
    if (s >= L_SEQ) return;
    const int tok = (s == 0) ? 0 : text[nn * L_SEQ + (s - 1)];
    const float v = emb[(size_t)tok * EMB + k];
    ce_f[idx] = v;
    ce_b[idx] = __float2bfloat16(v);
}

// ---------------- q = src @ Wq.T + bq ------------------------------------------
__global__ __launch_bounds__(256) void qproj_kernel(
    const float* __restrict__ src, const float* __restrict__ Wq,
    const float* __restrict__ bq, float* __restrict__ dst)
{
    __shared__ float xs[2][KSZ];
    const int tid = threadIdx.x;
    const int r0 = blockIdx.x * 2;
    xs[tid >> 7][tid & 127] = src[(size_t)(r0 + (tid >> 7)) * KSZ + (tid & 127)];
    __syncthreads();
    const int sub = tid >> 7, o = tid & 127;
    const float* wr = Wq + (size_t)o * KSZ;
    float acc = bq[o];
    #pragma unroll 8
    for (int k = 0; k < KSZ; k += 4) {
        const float4 w4 = *(const float4*)&wr[k];
        const float4 x4 = *(const float4*)&xs[sub][k];
        acc += w4.x * x4.x + w4.y * x4.y + w4.z * x4.z + w4.w * x4.w;
    }
    dst[(size_t)(r0 + sub) * KSZ + o] = acc;
}

// ---------------- flash attention ----------------------------------------------
__global__ __launch_bounds__(256) void attn_kernel(
    const float* __restrict__ q,      // [L][N][KSZ]
    const float* __restrict__ key,    // [T][N][KSZ]
    const float* __restrict__ values, // [T][N][VSZ]
    const int* __restrict__ rlen,
    float* __restrict__ ctx_f,        // [L][N][VSZ]
    __hip_bfloat16* __restrict__ ctx_b)
{
    __shared__ __align__(16) float q_s[52][128];
    __shared__ __align__(16) float Kt[TT][129];
    __shared__ __align__(16) float Vt[TT][129];
    __shared__ __align__(16) float es[52][68];
    __shared__ float mm[52], ss[52], al[52];
    const int tid = threadIdx.x;
    const int n = blockIdx.x >> 2;
    const int l0 = (blockIdx.x & 3) * 50;
    const int len = rlen[n];

    for (int idx = tid; idx < 52 * 128; idx += 256) {
        const int l = idx >> 7, k = idx & 127;
        q_s[l][k] = (l < 50) ? q[((size_t)(l0 + l) * NB + n) * KSZ + k] : 0.0f;
    }
    for (int l = tid; l < 52; l += 256) { mm[l] = -3.0e38f; ss[l] = 0.0f; }
    float acc[25];
    #pragma unroll
    for (int j = 0; j < 25; ++j) acc[j] = 0.0f;
    __syncthreads();

    const int lg = tid >> 6, lane = tid & 63;
    const int vv = tid & 127, hh = tid >> 7;
    const int nt = (len + TT - 1) / TT;

    for (int tt = 0; tt < nt; ++tt) {
        const int tb = tt * TT;
        const int valid = min(TT, len - tb);
        #pragma unroll
        for (int it = 0; it < 8; ++it) {
            const int idx4 = tid + it * 256;
            const int r = idx4 >> 5, c4 = (idx4 & 31) * 4;
            float4 kq = make_float4(0.f, 0.f, 0.f, 0.f);
            float4 vq = make_float4(0.f, 0.f, 0.f, 0.f);
            if (r < valid) {
                const size_t base = ((size_t)(tb + r) * NB + n) * 128 + c4;
                kq = *(const float4*)&key[base];
                vq = *(const float4*)&values[base];
            }
            Kt[r][c4 + 0] = kq.x; Kt[r][c4 + 1] = kq.y;
            Kt[r][c4 + 2] = kq.z; Kt[r][c4 + 3] = kq.w;
            Vt[r][c4 + 0] = vq.x; Vt[r][c4 + 1] = vq.y;
            Vt[r][c4 + 2] = vq.z; Vt[r][c4 + 3] = vq.w;
        }
        __syncthreads();
        {
            float e[13];
            #pragma unroll
            for (int j = 0; j < 13; ++j) e[j] = 0.0f;
            for (int k4 = 0; k4 < 128; k4 += 4) {
                const float c0 = Kt[lane][k4 + 0], c1 = Kt[lane][k4 + 1];
                const float c2 = Kt[lane][k4 + 2], c3 = Kt[lane][k4 + 3];
                #pragma unroll
                for (int j = 0; j < 13; ++j) {
                    const float4 q4 = *(const float4*)&q_s[lg * 13 + j][k4];
                    e[j] += c0 * q4.x + c1 * q4.y + c2 * q4.z + c3 * q4.w;
                }
            }
            #pragma unroll
            for (int j = 0; j < 13; ++j) {
                const int l = lg * 13 + j;
                float ev = (lane < valid) ? e[j] : -3.0e38f;
                #pragma unroll
                for (int off = 32; off; off >>= 1) ev = fmaxf(ev, __shfl_xor(ev, off, 64));
                const float mold = mm[l];
                const float mnew = fmaxf(mold, ev);
                const float p = (lane < valid) ? __expf(e[j] - mnew) : 0.0f;
                es[l][lane] = p;
                float ps = p;
                #pragma unroll
                for (int off = 32; off; off >>= 1) ps += __shfl_xor(ps, off, 64);
                if (lane == 0) {
                    const float a = __expf(mold - mnew);   // 0 on first tile
                    al[l] = a;
                    ss[l] = ss[l] * a + ps;
                    mm[l] = mnew;
                }
            }
        }
        __syncthreads();
        // ---- PV, V-hoisted: thread (vv,hh) owns l = hh+2j; es reads broadcast
        #pragma unroll
        for (int j = 0; j < 25; ++j) acc[j] *= al[hh + 2 * j];
        for (int t4 = 0; t4 < TT; t4 += 4) {
            const float v0 = Vt[t4 + 0][vv], v1 = Vt[t4 + 1][vv];
            const float v2 = Vt[t4 + 2][vv], v3 = Vt[t4 + 3][vv];
            #pragma unroll
            for (int j = 0; j < 25; ++j) {
                const float4 p4 = *(const float4*)&es[hh + 2 * j][t4];
                acc[j] += p4.x * v0 + p4.y * v1 + p4.z * v2 + p4.w * v3;
            }
        }
        __syncthreads();
    }
    #pragma unroll
    for (int j = 0; j < 25; ++j) {
        const int l = hh + 2 * j;
        const float r = acc[j] / ss[l];
        const size_t o = ((size_t)(l0 + l) * NB + n) * VSZ + vv;
        ctx_f[o] = r;
        ctx_b[o] = __float2bfloat16(r);
    }
}

// ---------------- persistent scan, split-counter protocol ----------------------
// 4 n-groups x (8 gates2 + 32 gates1). Uniform wave->K split. c-state in VGPRs.
// h1/h2 exchange via relaxed agent atomics. gates2 releases h1 (ctrR) right
// after its loads drain, so its epilogue is off gates1's critical path.
__global__ __launch_bounds__(256) void scan_persist(
    const __hip_bfloat16* __restrict__ Wc1, const __hip_bfloat16* __restrict__ Wc2,
    const float* __restrict__ bb1, const float* __restrict__ bb2,
    const __hip_bfloat16* __restrict__ ce_b, const __hip_bfloat16* __restrict__ ctx1_b,
    unsigned int* __restrict__ h1x, unsigned int* __restrict__ h2x,
    float* __restrict__ h2_all, int* __restrict__ bar)
{
    const int tid = threadIdx.x;
    const int w = tid >> 6;               // wave = K-slice
    const int lane = tid & 63;
    const int lrow = lane & 15;
    const int krow = (lane >> 4) * 8;
    const int rbase = (lane >> 4) * 4;
    __shared__ float gl[4][32][68];       // stride 68: 2-way (free) store pattern
    const int nl = tid >> 3, op = tid & 7;

    if (blockIdx.x < 32) {
        // ======== gates2: phase i (1..200) computes h2(i-1) ========
        const int grp = blockIdx.x >> 3;
        int* gb = bar + grp * 6 * 64;
        const int n0 = grp * 32;
        const int og = blockIdx.x & 7;
        // wave w: h1 chunks j=0..3 (ch w*128+j*32), h2 chunk j=4 (ch w*32)
        bf16x8 wf[20];
        #pragma unroll
        for (int t = 0; t < 4; ++t)
            #pragma unroll
            for (int j = 0; j < 5; ++j) {
                const int kk = (j < 4) ? (w * 128 + j * 32 + krow) : (512 + w * 32 + krow);
                wf[t * 5 + j] = LD8(Wc2 + (size_t)(t * 128 + og * 16 + lrow) * KK2 + kk);
            }
        const int oc = og * 16 + 2 * op;
        float bia[4][2];
        #pragma unroll
        for (int g = 0; g < 4; ++g) {
            bia[g][0] = bb2[g * 128 + oc];
            bia[g][1] = bb2[g * 128 + oc + 1];
        }
        float cst0 = 0.0f, cst1 = 0.0f;
        const unsigned int* h1e = h1x;
        const unsigned int* h1o = h1x + NB * HID / 2;
        const unsigned int* h2e = h2x;
        const unsigned int* h2o = h2x + NB * KSZ / 2;
        for (int i = 1; i <= L_SEQ; ++i) {
            if (tid == 0) spinw(gb, 8 * i, 8 * (i - 1), 5);
            __syncthreads();
            const int s2 = i - 1;
            const unsigned int* h1r = (i & 1) ? h1o : h1e;
            const unsigned int* h2r = (i & 1) ? h2o : h2e;
            unsigned int* h2w = (unsigned int*)((i & 1) ? h2e : h2o);
            const unsigned int* r0 = h1r + (n0 + lrow) * (HID / 2) + (w * 128 + krow) / 2;
            const unsigned int* r1 = h1r + (n0 + lrow + 16) * (HID / 2) + (w * 128 + krow) / 2;
            const bf16x8 a00 = LD8CC(r0), a01 = LD8CC(r0 + 16), a02 = LD8CC(r0 + 32), a03 = LD8CC(r0 + 48);
            const bf16x8 a10 = LD8CC(r1), a11 = LD8CC(r1 + 16), a12 = LD8CC(r1 + 32), a13 = LD8CC(r1 + 48);
            const bf16x8 g0 = LD8CC(h2r + (n0 + lrow) * (KSZ / 2) + (w * 32 + krow) / 2);
            const bf16x8 g1 = LD8CC(h2r + (n0 + lrow + 16) * (KSZ / 2) + (w * 32 + krow) / 2);
            asm volatile("s_waitcnt vmcnt(0)" ::: "memory");
            __syncthreads();
            if (tid == 0) CADD(gb + 4 * 64);      // ctrR: h1(i-1)/h2(i-2) reads done
            f32x4 acc0[4] = {{0,0,0,0},{0,0,0,0},{0,0,0,0},{0,0,0,0}};
            f32x4 acc1[4] = {{0,0,0,0},{0,0,0,0},{0,0,0,0},{0,0,0,0}};
            #pragma unroll
            for (int t = 0; t < 4; ++t) {
                acc0[t] = MFMA_BF16(a00, wf[t * 5 + 0], acc0[t]);
                acc0[t] = MFMA_BF16(a01, wf[t * 5 + 1], acc0[t]);
                acc0[t] = MFMA_BF16(a02, wf[t * 5 + 2], acc0[t]);
                acc0[t] = MFMA_BF16(a03, wf[t * 5 + 3], acc0[t]);
                acc0[t] = MFMA_BF16(g0,  wf[t * 5 + 4], acc0[t]);
                acc1[t] = MFMA_BF16(a10, wf[t * 5 + 0], acc1[t]);
                acc1[t] = MFMA_BF16(a11, wf[t * 5 + 1], acc1[t]);
                acc1[t] = MFMA_BF16(a12, wf[t * 5 + 2], acc1[t]);
                acc1[t] = MFMA_BF16(a13, wf[t * 5 + 3], acc1[t]);
                acc1[t] = MFMA_BF16(g1,  wf[t * 5 + 4], acc1[t]);
            }
            #pragma unroll
            for (int t = 0; t < 4; ++t)
                #pragma unroll
                for (int r = 0; r < 4; ++r) {
                    gl[w][rbase + r][t * 16 + lrow] = acc0[t][r];
                    gl[w][16 + rbase + r][t * 16 + lrow] = acc1[t][r];
                }
            __syncthreads();
            float sg[4][2];
            #pragma unroll
            for (int g = 0; g < 4; ++g) {
                float2 s0 = *(float2*)&gl[0][nl][g * 16 + 2 * op];
                float2 s1 = *(float2*)&gl[1][nl][g * 16 + 2 * op];
                float2 s2_ = *(float2*)&gl[2][nl][g * 16 + 2 * op];
                float2 s3 = *(float2*)&gl[3][nl][g * 16 + 2 * op];
                sg[g][0] = s0.x + s1.x + s2_.x + s3.x + bia[g][0];
                sg[g][1] = s0.y + s1.y + s2_.y + s3.y + bia[g][1];
            }
            const float cn0 = sig_(sg[1][0]) * cst0 + sig_(sg[0][0]) * tanh_fast(sg[2][0]);
            const float cn1 = sig_(sg[1][1]) * cst1 + sig_(sg[0][1]) * tanh_fast(sg[2][1]);
            const float hv0 = sig_(sg[3][0]) * tanh_fast(cn0);
            const float hv1 = sig_(sg[3][1]) * tanh_fast(cn1);
            cst0 = cn0; cst1 = cn1;
            const int nn = n0 + nl;
            union { unsigned int u; __hip_bfloat16 b[2]; } pk;
            pk.b[0] = __float2bfloat16(hv0);
            pk.b[1] = __float2bfloat16(hv1);
            ST4CC(h2w + nn * (KSZ / 2) + oc / 2, pk.u);
            *(float2*)&h2_all[((size_t)s2 * NB + nn) * KSZ + oc] = make_float2(hv0, hv1);
            asm volatile("s_waitcnt vmcnt(0)" ::: "memory");
            __syncthreads();
            if (tid == 0) CADD(gb + 5 * 64);      // ctr2: h2(i-1) published
        }
    } else {
        // ======== gates1: phase i (0..199) computes h1(i) ========
        const int bid2 = blockIdx.x - 32;
        const int grp = bid2 >> 5;
        int* gb = bar + grp * 6 * 64;
        const int n0 = grp * 32;
        const int og = bid2 & 31;
        int* myctr = gb + (og >> 3) * 64;
        // wave w: cached chunks j=0,1 (ce/ctx ch w*64+j*32), h1 chunks j=2..5
        bf16x8 wf[24];
        #pragma unroll
        for (int t = 0; t < 4; ++t)
            #pragma unroll
            for (int j = 0; j < 6; ++j) {
                const int kk = (j < 2) ? (w * 64 + j * 32 + krow)
                                       : (256 + w * 128 + (j - 2) * 32 + krow);
                wf[t * 6 + j] = LD8(Wc1 + (size_t)(t * 512 + og * 16 + lrow) * KK1 + kk);
            }
        const int oc = og * 16 + 2 * op;
        float bia[4][2];
        #pragma unroll
        for (int g = 0; g < 4; ++g) {
            bia[g][0] = bb1[g * 512 + oc];
            bia[g][1] = bb1[g * 512 + oc + 1];
        }
        float cst0 = 0.0f, cst1 = 0.0f;
        const unsigned int* h1e = h1x;
        const unsigned int* h1o = h1x + NB * HID / 2;
        for (int i = 0; i < L_SEQ; ++i) {
            // prefetch ce/ctx (no h1 dependency) before the spin
            bf16x8 pj0h0, pj1h0, pj0h1, pj1h1;
            if (w < 2) {
                const __hip_bfloat16* s0 = ce_b + ((size_t)i * NB + n0 + lrow) * EMB + w * 64 + krow;
                const __hip_bfloat16* s1 = ce_b + ((size_t)i * NB + n0 + lrow + 16) * EMB + w * 64 + krow;
                pj0h0 = LD8(s0); pj1h0 = LD8(s0 + 32);
                pj0h1 = LD8(s1); pj1h1 = LD8(s1 + 32);
            } else {
                const __hip_bfloat16* s0 = ctx1_b + ((size_t)i * NB + n0 + lrow) * VSZ + (w - 2) * 64 + krow;
                const __hip_bfloat16* s1 = ctx1_b + ((size_t)i * NB + n0 + lrow + 16) * VSZ + (w - 2) * 64 + krow;
                pj0h0 = LD8(s0); pj1h0 = LD8(s0 + 32);
                pj0h1 = LD8(s1); pj1h1 = LD8(s1 + 32);
            }
            if (i) {
                if (tid == 0) spinw(gb, 8 * i, 8 * (i - 1), 4);
                __syncthreads();
            }
            const unsigned int* h1r = (i & 1) ? h1o : h1e;
            unsigned int* h1w = (unsigned int*)((i & 1) ? h1e : h1o);
            const unsigned int* r0 = h1r + (n0 + lrow) * (HID / 2) + (w * 128 + krow) / 2;
            const unsigned int* r1 = h1r + (n0 + lrow + 16) * (HID / 2) + (w * 128 + krow) / 2;
            const bf16x8 a20 = LD8CC(r0), a30 = LD8CC(r0 + 16), a40 = LD8CC(r0 + 32), a50 = LD8CC(r0 + 48);
            const bf16x8 a21 = LD8CC(r1), a31 = LD8CC(r1 + 16), a41 = LD8CC(r1 + 32), a51 = LD8CC(r1 + 48);
            f32x4 acc0[4] = {{0,0,0,0},{0,0,0,0},{0,0,0,0},{0,0,0,0}};
            f32x4 acc1[4] = {{0,0,0,0},{0,0,0,0},{0,0,0,0},{0,0,0,0}};
            #pragma unroll
            for (int t = 0; t < 4; ++t) {
                acc0[t] = MFMA_BF16(pj0h0, wf[t * 6 + 0], acc0[t]);
                acc0[t] = MFMA_BF16(pj1h0, wf[t * 6 + 1], acc0[t]);
                acc0[t] = MFMA_BF16(a20, wf[t * 6 + 2], acc0[t]);
                acc0[t] = MFMA_BF16(a30, wf[t * 6 + 3], acc0[t]);
                acc0[t] = MFMA_BF16(a40, wf[t * 6 + 4], acc0[t]);
                acc0[t] = MFMA_BF16(a50, wf[t * 6 + 5], acc0[t]);
                acc1[t] = MFMA_BF16(pj0h1, wf[t * 6 + 0], acc1[t]);
                acc1[t] = MFMA_BF16(pj1h1, wf[t * 6 + 1], acc1[t]);
                acc1[t] = MFMA_BF16(a21, wf[t * 6 + 2], acc1[t]);
                acc1[t] = MFMA_BF16(a31, wf[t * 6 + 3], acc1[t]);
                acc1[t] = MFMA_BF16(a41, wf[t * 6 + 4], acc1[t]);
                acc1[t] = MFMA_BF16(a51, wf[t * 6 + 5], acc1[t]);
            }
            #pragma unroll
            for (int t = 0; t < 4; ++t)
                #pragma unroll
                for (int r = 0; r < 4; ++r) {
                    gl[w][rbase + r][t * 16 + lrow] = acc0[t][r];
                    gl[w][16 + rbase + r][t * 16 + lrow] = acc1[t][r];
                }
            __syncthreads();
            float sg[4][2];
            #pragma unroll
            for (int g = 0; g < 4; ++g) {
                float2 s0 = *(float2*)&gl[0][nl][g * 16 + 2 * op];
                float2 s1 = *(float2*)&gl[1][nl][g * 16 + 2 * op];
                float2 s2_ = *(float2*)&gl[2][nl][g * 16 + 2 * op];
                float2 s3 = *(float2*)&gl[3][nl][g * 16 + 2 * op];
                sg[g][0] = s0.x + s1.x + s2_.x + s3.x + bia[g][0];
                sg[g][1] = s0.y + s1.y + s2_.y + s3.y + bia[g][1];
            }
            const float cn0 = sig_(sg[1][0]) * cst0 + sig_(sg[0][0]) * tanh_fast(sg[2][0]);
            const float cn1 = sig_(sg[1][1]) * cst1 + sig_(sg[0][1]) * tanh_fast(sg[2][1]);
            const float hv0 = sig_(sg[3][0]) * tanh_fast(cn0);
            const float hv1 = sig_(sg[3][1]) * tanh_fast(cn1);
            cst0 = cn0; cst1 = cn1;
            union { unsigned int u; __hip_bfloat16 b[2]; } pk;
            pk.b[0] = __float2bfloat16(hv0);
            pk.b[1] = __float2bfloat16(hv1);
            ST4CC(h1w + (n0 + nl) * (HID / 2) + oc / 2, pk.u);
            asm volatile("s_waitcnt vmcnt(0)" ::: "memory");
            __syncthreads();
            if (tid == 0) CADD(myctr);            // ctr1 sub: h1(i) published
        }
    }
}

// ---------------- outpred ------------------------------------------------------
__global__ __launch_bounds__(256) void outpred_kernel(
    const float* __restrict__ h2_all, const float* __restrict__ ctx2,
    const float* __restrict__ Wfc, const float* __restrict__ bfc,
    const float* __restrict__ emb, const float* __restrict__ b_out,
    float* __restrict__ out)
{
    __shared__ float xs[2][256];
    __shared__ float os[2][EMB];
    const int tid = threadIdx.x;
    const int r0 = blockIdx.x * 2;
    const int sub = tid >> 7, lane = tid & 127;
    const int r = r0 + sub;
    xs[sub][lane] = h2_all[(size_t)r * KSZ + lane];
    xs[sub][128 + lane] = ctx2[(size_t)r * VSZ + lane];
    __syncthreads();
    const float* wr = Wfc + (size_t)lane * 256;
    float acc = bfc[lane];
    #pragma unroll 8
    for (int k = 0; k < 256; k += 4) {
        const float4 w4 = *(const float4*)&wr[k];
        const float4 x4 = *(const float4*)&xs[sub][k];
        acc += w4.x * x4.x + w4.y * x4.y + w4.z * x4.z + w4.w * x4.w;
    }
    acc = fminf(1.0f, fmaxf(-1.0f, acc));
    os[sub][lane] = acc;
    __syncthreads();
    if (lane < VOCAB) {
        const float* er = emb + (size_t)lane * EMB;
        float a = b_out[lane];
        #pragma unroll 8
        for (int e = 0; e < EMB; e += 4) {
            const float4 e4 = *(const float4*)&er[e];
            const float4 x4 = *(const float4*)&os[sub][e];
            a += e4.x * x4.x + e4.y * x4.y + e4.z * x4.z + e4.w * x4.w;
        }
        const int s = r >> 7, nn = r & 127;
        out[((size_t)nn * L_SEQ + s) * VOCAB + lane] = a;
    }
}

extern "C" void kernel_launch(void* const* d_in, const int* in_sizes, int n_in,
                              void* d_out, int out_size, void* d_ws, size_t ws_size,
                              hipStream_t stream)
{
    (void)in_sizes; (void)n_in; (void)out_size; (void)ws_size;
    const float* key_proj = (const float*)d_in[0];
    const float* values   = (const float*)d_in[1];
    const int*   rlen     = (const int*)d_in[2];
    const int*   text     = (const int*)d_in[3];
    const float* emb      = (const float*)d_in[4];
    const float* Wq    = (const float*)d_in[5];
    const float* bq    = (const float*)d_in[6];
    const float* Wih1  = (const float*)d_in[7];
    const float* Whh1  = (const float*)d_in[8];
    const float* bih1  = (const float*)d_in[9];
    const float* bhh1  = (const float*)d_in[10];
    const float* Wih2  = (const float*)d_in[11];
    const float* Whh2  = (const float*)d_in[12];
    const float* bih2  = (const float*)d_in[13];
    const float* bhh2  = (const float*)d_in[14];
    const float* Wfc   = (const float*)d_in[15];
    const float* bfc   = (const float*)d_in[16];
    const float* b_out = (const float*)d_in[17];
    float* out = (float*)d_out;

    char* p = (char*)d_ws;
    auto take = [&p](size_t bytes) -> char* {
        char* r = p;
        p += (bytes + 255) & ~((size_t)255);
        return r;
    };
    float* ce_f  = (float*)take((size_t)L_SEQ * NB * EMB * 4);
    __hip_bfloat16* ce_b  = (__hip_bfloat16*)take((size_t)L_SEQ * NB * EMB * 2);
    __hip_bfloat16* ctx_b = (__hip_bfloat16*)take((size_t)L_SEQ * NB * VSZ * 2);
    float* ctx_f  = (float*)take((size_t)L_SEQ * NB * VSZ * 4);
    float* qbuf   = (float*)take((size_t)L_SEQ * NB * KSZ * 4);
    float* h2_all = (float*)take((size_t)L_SEQ * NB * KSZ * 4);
    __hip_bfloat16* Wc1 = (__hip_bfloat16*)take((size_t)G1 * KK1 * 2);
    __hip_bfloat16* Wc2 = (__hip_bfloat16*)take((size_t)G2 * KK2 * 2);
    float* bb1 = (float*)take(G1 * 4);
    float* bb2 = (float*)take(G2 * 4);
    unsigned int* h1x = (unsigned int*)take((size_t)2 * NB * HID / 2 * 4);
    unsigned int* h2x = (unsigned int*)take((size_t)2 * NB * KSZ / 2 * 4);
    int* bar = (int*)take(8192);

    prep_kernel<<<6144, 256, 0, stream>>>(Wih1, Whh1, bih1, bhh1, Wih2, Whh2,
                                          bih2, bhh2, Wc1, Wc2, bb1, bb2,
                                          h1x, h2x, bar);
    ce_gather<<<12800, 256, 0, stream>>>(text, emb, ce_f, ce_b);
    qproj_kernel<<<12800, 256, 0, stream>>>(ce_f, Wq, bq, qbuf);
    attn_kernel<<<512, 256, 0, stream>>>(qbuf, key_proj, values, rlen, ctx_f, ctx_b);
    scan_persist<<<NBLK, 256, 0, stream>>>(Wc1, Wc2, bb1, bb2, ce_b, ctx_b,
                                           h1x, h2x, h2_all, bar);
    qproj_kernel<<<12800, 256, 0, stream>>>(h2_all, Wq, bq, qbuf);
    attn_kernel<<<512, 256, 0, stream>>>(qbuf, key_proj, values, rlen, ctx_f, ctx_b);
    outpred_kernel<<<12800, 256, 0, stream>>>(h2_all, ctx_f, Wfc, bfc, emb, b_out, out);
}